// Round 12
// baseline (432.730 us; speedup 1.0000x reference)
//
#include <hip/hip_runtime.h>
#include <math.h>

// R11 = R9 (K=6 fusion, 8 launches, all-fp16-LDS exchange, verified absmax
// 0.015625) with ONE change: __launch_bounds__(512, 2) instead of (512, 4).
// Theory: the 2nd arg acts CUDA-style (min blocks/CU). (512,4) forced a
// 64-VGPR cap -> R8/R9's slot arrays spilled to scratch (the 150-450 MB/dispatch
// phantom FETCH/WRITE). (512,2) -> 16 waves/CU -> 128-VGPR cap; ~100 live
// VGPRs fit. LDS 55.3 KB still limits to 2 blocks/CU, so occupancy unchanged.
#define XDIM 160
#define YDIM 160
#define TDIM 16
#define NB 2
#define T_ITERS 48
#define TILE 10
#define KFUSE 6
#define S1 20             // slot region side = TILE + 2*(KFUSE-1)
#define S0 22             // xbar staging side = S1 + 2
#define TPT (XDIM / TILE) // 16
#define NTHR 512
#define NSLOT 4           // ceil(20*20*4 / 512); last slot partially masked

constexpr int VOL  = XDIM * YDIM * TDIM;  // 409600
constexpr int NX   = NB * VOL;            // 819200
constexpr int NBLK = NB * TPT * TPT;      // 512 blocks

typedef _Float16 hreal;
typedef _Float16 half4 __attribute__((ext_vector_type(4)));

__device__ __forceinline__ float clampl(float v, float l) {
    return fminf(fmaxf(v, -l), l);
}
__device__ __forceinline__ int wrap(int v) {  // v in [-6, 166)
    return v < 0 ? v + XDIM : (v >= XDIM ? v - XDIM : v);
}
__device__ __forceinline__ void ld4(const float* p, float* d) {
    float4 v = *(const float4*)p;
    d[0] = v.x; d[1] = v.y; d[2] = v.z; d[3] = v.w;
}
__device__ __forceinline__ void st4(float* p, const float* s) {
    *(float4*)p = make_float4(s[0], s[1], s[2], s[3]);
}
__device__ __forceinline__ void h2f4(const hreal* p, float* d) {
    half4 v = *(const half4*)p;
    d[0] = (float)v.x; d[1] = (float)v.y; d[2] = (float)v.z; d[3] = (float)v.w;
}
__device__ __forceinline__ void f2h4(hreal* p, const float* s) {
    half4 v;
    v.x = (hreal)s[0]; v.y = (hreal)s[1]; v.z = (hreal)s[2]; v.w = (hreal)s[3];
    *(half4*)p = v;
}

__global__ __launch_bounds__(256) void init_kernel(
    const float* __restrict__ x, const float* __restrict__ lam,
    float* __restrict__ pA, float* __restrict__ xA,
    hreal* __restrict__ xbAh, hreal* __restrict__ qAh,
    hreal* __restrict__ lamh, hreal* __restrict__ xnh)
{
    int i = blockIdx.x * blockDim.x + threadIdx.x;
    if (i < NX) {
        float v = x[i];
        pA[i] = v; xA[i] = v;
        xbAh[i] = (hreal)v;
        xnh[i]  = (hreal)v;
    }
    if (i < 3 * NX) {
        qAh[i]  = (hreal)0.f;
        lamh[i] = (hreal)lam[i];
    }
}

__global__ __launch_bounds__(NTHR, 2) void pd_step6(
    const hreal* __restrict__ xnh, const hreal* __restrict__ lamh,
    const float* __restrict__ pIn, float* __restrict__ pOut,
    const float* __restrict__ xIn, float* __restrict__ xOut,
    const hreal* __restrict__ xbIn, hreal* __restrict__ xbOut,
    const hreal* __restrict__ qIn, hreal* __restrict__ qOut,
    float sigma, float inv1ps, float tau, float theta)
{
    __shared__ __align__(16) hreal xbS[S0 * S0 * TDIM];        // 15488 B
    __shared__ __align__(16) hreal q0S[(S1 + 1) * S1 * TDIM];  // 13440 B, (lx+1)*S1+ly
    __shared__ __align__(16) hreal q1S[S1 * (S1 + 1) * TDIM];  // 13440 B, lx*(S1+1)+(ly+1)
    __shared__ __align__(16) hreal q2S[S1 * S1 * TDIM];        // 12800 B, lx*S1+ly

    const int tid = threadIdx.x;
    const int b   = blockIdx.x / (TPT * TPT);
    const int rem = blockIdx.x % (TPT * TPT);
    const int X0  = (rem / TPT) * TILE;
    const int Y0  = (rem % TPT) * TILE;
    const int xbase = b * VOL, qbase = b * 3 * VOL;

    const int t0 = (tid & 3) * 4;

    // ---- phase 0: stage xbar / q0 / q1 / q2 into fp16 LDS (16B chunks) ----
    for (int s = tid; s < S0 * S0 * 2; s += NTHR) {
        int hf = s & 1, ln = s >> 1;
        int rx = ln / S0, ry = ln % S0;
        int gx = wrap(X0 - 6 + rx), gy = wrap(Y0 - 6 + ry);
        *(uint4*)(xbS + ln * TDIM + hf * 8) =
            *(const uint4*)(xbIn + xbase + (gx * YDIM + gy) * TDIM + hf * 8);
    }
    for (int s = tid; s < (S1 + 1) * S1 * 2; s += NTHR) {
        int hf = s & 1, ln = s >> 1;
        int sx = ln / S1, sy = ln % S1;
        int gx = wrap(X0 - 6 + sx), gy = wrap(Y0 - 5 + sy);
        *(uint4*)(q0S + ln * TDIM + hf * 8) =
            *(const uint4*)(qIn + qbase + (gx * YDIM + gy) * TDIM + hf * 8);
    }
    for (int s = tid; s < S1 * (S1 + 1) * 2; s += NTHR) {
        int hf = s & 1, ln = s >> 1;
        int sx = ln / (S1 + 1), sy = ln % (S1 + 1);
        int gx = wrap(X0 - 5 + sx), gy = wrap(Y0 - 6 + sy);
        *(uint4*)(q1S + ln * TDIM + hf * 8) =
            *(const uint4*)(qIn + qbase + VOL + (gx * YDIM + gy) * TDIM + hf * 8);
    }
    for (int s = tid; s < S1 * S1 * 2; s += NTHR) {
        int hf = s & 1, ln = s >> 1;
        int lx = ln / S1, ly = ln % S1;
        int gx = wrap(X0 - 5 + lx), gy = wrap(Y0 - 5 + ly);
        *(uint4*)(q2S + ln * TDIM + hf * 8) =
            *(const uint4*)(qIn + qbase + 2 * VOL + (gx * YDIM + gy) * TDIM + hf * 8);
    }

    // ---- phase 0b: per-slot register state (p, x fp32; lam/xn packed) ----
    float p[NSLOT][4], xv[NSLOT][4];
    half4 XNr[NSLOT], L0r[NSLOT], L1r[NSLOT], L2r[NSLOT];
    #pragma unroll
    for (int m = 0; m < NSLOT; ++m) {
        int line = m * (NTHR / 4) + (tid >> 2);
        if (line < S1 * S1) {
            int lx = line / S1, ly = line % S1;
            int gx = wrap(X0 - (KFUSE - 1) + lx), gy = wrap(Y0 - (KFUSE - 1) + ly);
            int off  = xbase + (gx * YDIM + gy) * TDIM + t0;
            int qoff = qbase + (gx * YDIM + gy) * TDIM + t0;
            ld4(pIn + off, p[m]);
            ld4(xIn + off, xv[m]);
            XNr[m] = *(const half4*)(xnh + off);
            L0r[m] = *(const half4*)(lamh + qoff);
            L1r[m] = *(const half4*)(lamh + qoff + VOL);
            L2r[m] = *(const half4*)(lamh + qoff + 2 * VOL);
        }
    }

    // ring lambdas (level-1 backward q rings at lx=-1 / ly=-1)
    half4 LRr;
    if (tid < S1 * 4) {                        // 80 tasks: q0 ring
        int rly = tid >> 2;
        LRr = *(const half4*)(lamh + qbase +
              (wrap(X0 - 6) * YDIM + wrap(Y0 - 5 + rly)) * TDIM + t0);
    } else if (tid < 2 * S1 * 4) {             // 80 tasks: q1 ring
        int rlx = (tid - S1 * 4) >> 2;
        LRr = *(const half4*)(lamh + qbase + VOL +
              (wrap(X0 - 5 + rlx) * YDIM + wrap(Y0 - 6)) * TDIM + t0);
    }

    __syncthreads();

    // ---- level loop k = 1..6 ----
    for (int k = 1; k <= KFUSE; ++k) {
        const int lo = k - 1, hi = S1 + 1 - k;

        // ===== phase B: update q0,q1,q2 (LDS RMW), p (regs) =====
        if (k == 1) {
            if (tid < S1 * 4) {
                int rly = tid >> 2;
                float qr[4], xbc[4], xpx[4];
                h2f4(q0S + (0 * S1 + rly) * TDIM + t0, qr);
                h2f4(xbS + (0 * S0 + (rly + 1)) * TDIM + t0, xbc);
                h2f4(xbS + (1 * S0 + (rly + 1)) * TDIM + t0, xpx);
                #pragma unroll
                for (int j = 0; j < 4; ++j)
                    qr[j] = clampl(qr[j] + sigma * (xpx[j] - xbc[j]), (float)LRr[j]);
                f2h4(q0S + (0 * S1 + rly) * TDIM + t0, qr);
            } else if (tid < 2 * S1 * 4) {
                int rlx = (tid - S1 * 4) >> 2;
                float qr[4], xbc[4], xpy[4];
                h2f4(q1S + (rlx * (S1 + 1) + 0) * TDIM + t0, qr);
                h2f4(xbS + ((rlx + 1) * S0 + 0) * TDIM + t0, xbc);
                h2f4(xbS + ((rlx + 1) * S0 + 1) * TDIM + t0, xpy);
                #pragma unroll
                for (int j = 0; j < 4; ++j)
                    qr[j] = clampl(qr[j] + sigma * (xpy[j] - xbc[j]), (float)LRr[j]);
                f2h4(q1S + (rlx * (S1 + 1) + 0) * TDIM + t0, qr);
            }
        }

        #pragma unroll
        for (int m = 0; m < NSLOT; ++m) {
            int line = m * (NTHR / 4) + (tid >> 2);
            bool act = line < S1 * S1;
            int lx = act ? line / S1 : 0, ly = act ? line % S1 : 0;
            bool inX = lx >= lo && lx < hi, inY = ly >= lo && ly < hi;
            bool aq0 = act && inY && (lx >= lo - 1) && (lx < hi);
            bool aq1 = act && inX && (ly >= lo - 1) && (ly < hi);
            bool ax  = act && inX && inY;

            const int xc = ((lx + 1) * S0 + (ly + 1)) * TDIM;
            float xbo[4];
            h2f4(xbS + xc + t0, xbo);

            if (aq0) {
                float xpx[4], qv[4];
                h2f4(xbS + ((lx + 2) * S0 + (ly + 1)) * TDIM + t0, xpx);
                h2f4(q0S + ((lx + 1) * S1 + ly) * TDIM + t0, qv);
                #pragma unroll
                for (int j = 0; j < 4; ++j)
                    qv[j] = clampl(qv[j] + sigma * (xpx[j] - xbo[j]),
                                   (float)L0r[m][j]);
                f2h4(q0S + ((lx + 1) * S1 + ly) * TDIM + t0, qv);
            }
            if (aq1) {
                float xpy[4], qv[4];
                h2f4(xbS + ((lx + 1) * S0 + (ly + 2)) * TDIM + t0, xpy);
                h2f4(q1S + (lx * (S1 + 1) + (ly + 1)) * TDIM + t0, qv);
                #pragma unroll
                for (int j = 0; j < 4; ++j)
                    qv[j] = clampl(qv[j] + sigma * (xpy[j] - xbo[j]),
                                   (float)L1r[m][j]);
                f2h4(q1S + (lx * (S1 + 1) + (ly + 1)) * TDIM + t0, qv);
            }
            if (ax) {
                float xb_tp = (float)xbS[xc + ((t0 + 4) & (TDIM - 1))];
                float qv[4];
                h2f4(q2S + line * TDIM + t0, qv);
                #pragma unroll
                for (int j = 0; j < 4; ++j) {
                    float gt = ((j < 3) ? xbo[j + 1] : xb_tp) - xbo[j];
                    qv[j] = clampl(qv[j] + sigma * gt, (float)L2r[m][j]);
                    p[m][j] = (p[m][j] + sigma * (xbo[j] - (float)XNr[m][j]))
                              * inv1ps;
                }
                f2h4(q2S + line * TDIM + t0, qv);
            }
        }
        __syncthreads();

        // ===== phase C: read new q from LDS; update x, xbar =====
        #pragma unroll
        for (int m = 0; m < NSLOT; ++m) {
            int line = m * (NTHR / 4) + (tid >> 2);
            bool act = line < S1 * S1;
            int lx = act ? line / S1 : 0, ly = act ? line % S1 : 0;
            bool ax = act && lx >= lo && lx < hi && ly >= lo && ly < hi;
            if (ax) {
                float q0o[4], q0b[4], q1o[4], q1b[4], q2o[4];
                h2f4(q0S + ((lx + 1) * S1 + ly) * TDIM + t0, q0o);
                h2f4(q0S + (lx * S1 + ly) * TDIM + t0, q0b);
                h2f4(q1S + (lx * (S1 + 1) + (ly + 1)) * TDIM + t0, q1o);
                h2f4(q1S + (lx * (S1 + 1) + ly) * TDIM + t0, q1b);
                h2f4(q2S + line * TDIM + t0, q2o);
                float q2tm = (float)q2S[line * TDIM + ((t0 + TDIM - 1) & (TDIM - 1))];

                float xbn[4];
                #pragma unroll
                for (int j = 0; j < 4; ++j) {
                    float q2p = (j == 0) ? q2tm : q2o[j - 1];
                    float div = (q0b[j] - q0o[j]) + (q1b[j] - q1o[j])
                              + (q2p - q2o[j]);
                    float xnew = xv[m][j] - tau * (p[m][j] + div);
                    xbn[j] = xnew + theta * (xnew - xv[m][j]);
                    xv[m][j] = xnew;
                }
                if (k < KFUSE) {
                    f2h4(xbS + ((lx + 1) * S0 + (ly + 1)) * TDIM + t0, xbn);
                } else {
                    // k==6: active region IS the 10x10 center -> output
                    int gx = X0 + lx - (KFUSE - 1), gy = Y0 + ly - (KFUSE - 1);
                    int off  = xbase + (gx * YDIM + gy) * TDIM + t0;
                    int qoff = qbase + (gx * YDIM + gy) * TDIM + t0;
                    st4(pOut + off, p[m]);
                    st4(xOut + off, xv[m]);
                    f2h4(xbOut + off, xbn);
                    f2h4(qOut + qoff, q0o);
                    f2h4(qOut + qoff + VOL, q1o);
                    f2h4(qOut + qoff + 2 * VOL, q2o);
                }
            }
        }
        if (k < KFUSE) __syncthreads();
    }
}

extern "C" void kernel_launch(void* const* d_in, const int* in_sizes, int n_in,
                              void* d_out, int out_size, void* d_ws, size_t ws_size,
                              hipStream_t stream) {
    const float* x   = (const float*)d_in[0];
    const float* lam = (const float*)d_in[1];
    float* out = (float*)d_out;
    float* ws  = (float*)d_ws;

    // ws: [pA|pB|xB] fp32 (3*NX floats) then fp16 region (12*NX halves)
    float* pA  = ws;
    float* pB  = ws + (size_t)NX;
    float* xBb = ws + (size_t)2 * NX;
    float* xAb = out;   // 8 launches: final (j=7, odd) writes A family -> d_out
    hreal* hb  = (hreal*)(ws + (size_t)3 * NX);
    hreal* xbAh = hb;
    hreal* xbBh = hb + (size_t)NX;
    hreal* qAh  = hb + (size_t)2 * NX;
    hreal* qBh  = hb + (size_t)5 * NX;
    hreal* lamh = hb + (size_t)8 * NX;
    hreal* xnh  = hb + (size_t)11 * NX;

    const double s10 = 1.0 / (1.0 + exp(-10.0));
    const double L   = sqrt(13.0);
    float sigma  = (float)(s10 / L);
    float tau    = sigma;
    float theta  = (float)s10;
    float inv1ps = (float)(1.0 / (1.0 + s10 / L));

    init_kernel<<<(3 * NX + 255) / 256, 256, 0, stream>>>(
        x, lam, pA, xAb, xbAh, qAh, lamh, xnh);

    for (int j = 0; j < T_ITERS / KFUSE; ++j) {   // 8 launches
        const bool e = (j & 1) == 0;
        pd_step6<<<NBLK, NTHR, 0, stream>>>(
            xnh, lamh,
            e ? pA : pB,   e ? pB : pA,
            e ? xAb : xBb, e ? xBb : xAb,
            e ? xbAh : xbBh, e ? xbBh : xbAh,
            e ? qAh : qBh,  e ? qBh : qAh,
            sigma, inv1ps, tau, theta);
    }
}

// Round 13
// 253.331 us; speedup vs baseline: 1.7082x; 1.7082x over previous
//
#include <hip/hip_runtime.h>
#include <math.h>

// R12 = R10 (K=4 fusion, 512-thr blocks, fp32 LDS exchange, 2 slots/thread,
// first/last-launch trims, 253 us) with ONE change:
//   __launch_bounds__(NTHR, 2)  [was (NTHR, 4)]
// R11 proved the 2nd arg caps VGPRs CUDA-style: (512,4) -> 64 VGPR cap.
// R10's live state (~86 VGPR) was silently spilling under that cap; LDS
// (54.25 KB) limits occupancy to 2 blocks/CU anyway, so (512,2) costs nothing.
#define XDIM 160
#define YDIM 160
#define TDIM 16
#define NB 2
#define T_ITERS 48
#define TILE 10
#define R1S 16            // level-1 region side (TILE+6)
#define R0S 18            // xbar staging side (TILE+8)
#define TPT (XDIM / TILE) // 16 tiles per side
#define NTHR 512

constexpr int VOL  = XDIM * YDIM * TDIM;  // 409600
constexpr int NX   = NB * VOL;            // 819200
constexpr int NBLK = NB * TPT * TPT;      // 512 blocks

typedef _Float16 hreal;
typedef _Float16 half4 __attribute__((ext_vector_type(4)));

__device__ __forceinline__ float clampl(float v, float l) {
    return fminf(fmaxf(v, -l), l);
}
__device__ __forceinline__ int wrap(int v) {  // v in [-4, 164)
    return v < 0 ? v + XDIM : (v >= XDIM ? v - XDIM : v);
}
__device__ __forceinline__ void ld4(const float* p, float* d) {
    float4 v = *(const float4*)p;
    d[0] = v.x; d[1] = v.y; d[2] = v.z; d[3] = v.w;
}
__device__ __forceinline__ void st4(float* p, const float* s) {
    *(float4*)p = make_float4(s[0], s[1], s[2], s[3]);
}
__device__ __forceinline__ void h2f4(const hreal* p, float* d) {
    half4 v = *(const half4*)p;
    d[0] = (float)v.x; d[1] = (float)v.y; d[2] = (float)v.z; d[3] = (float)v.w;
}

// init: only the iteration-constant fp16 copies (lambda, xnoisy).
__global__ __launch_bounds__(256) void init_kernel(
    const float* __restrict__ x, const float* __restrict__ lam,
    hreal* __restrict__ lamh, hreal* __restrict__ xnh)
{
    int i = blockIdx.x * blockDim.x + threadIdx.x;
    if (i < NX) xnh[i] = (hreal)x[i];
    if (i < 3 * NX) lamh[i] = (hreal)lam[i];
}

__global__ __launch_bounds__(NTHR, 2) void pd_step4(
    const hreal* __restrict__ xnh, const hreal* __restrict__ lamh,
    const float* __restrict__ xraw,
    const float* __restrict__ pIn, float* __restrict__ pOut,
    const float* __restrict__ xIn, float* __restrict__ xOut,
    const hreal* __restrict__ xbIn, hreal* __restrict__ xbOut,
    const hreal* __restrict__ qIn, hreal* __restrict__ qOut,
    float sigma, float inv1ps, float tau, float theta,
    int firstIter, int lastIter)
{
    __shared__ float xbS[R0S * R0S * TDIM];        // 20.25 KB
    __shared__ float q0S[(R1S + 1) * R1S * TDIM];  // 17 KB, (lx+1)*16+ly
    __shared__ float q1S[R1S * (R1S + 1) * TDIM];  // 17 KB, lx*17+(ly+1)

    const int tid = threadIdx.x;
    const int b   = blockIdx.x / (TPT * TPT);
    const int rem = blockIdx.x % (TPT * TPT);
    const int X0  = (rem / TPT) * TILE;
    const int Y0  = (rem % TPT) * TILE;
    const int xbase = b * VOL, qbase = b * 3 * VOL;

    const int qd = tid & 3, t0 = qd * 4;
    const int lane  = tid & 63;
    const int upSrc = (lane & 60) | ((lane + 1) & 3);
    const int dnSrc = (lane & 60) | ((lane + 3) & 3);

    // ---- phase 0: stage xbar_0 / q0_0 / q1_0 into LDS ----
    if (firstIter) {
        for (int s = tid; s < R0S * R0S * 4; s += NTHR) {
            int sq = s & 3, ln = s >> 2;
            int rx = ln / R0S, ry = ln % R0S;
            int gx = wrap(X0 - 4 + rx), gy = wrap(Y0 - 4 + ry);
            float v[4];
            ld4(xraw + xbase + (gx * YDIM + gy) * TDIM + sq * 4, v);
            #pragma unroll
            for (int j = 0; j < 4; ++j) v[j] = (float)(hreal)v[j];
            st4(xbS + ln * TDIM + sq * 4, v);
        }
        for (int s = tid; s < 17 * 16 * 4; s += NTHR) {
            int sq = s & 3, ln = s >> 2;
            float z[4] = {0.f, 0.f, 0.f, 0.f};
            st4(q0S + ln * TDIM + sq * 4, z);
        }
        for (int s = tid; s < 16 * 17 * 4; s += NTHR) {
            int sq = s & 3, ln = s >> 2;
            float z[4] = {0.f, 0.f, 0.f, 0.f};
            st4(q1S + ln * TDIM + sq * 4, z);
        }
    } else {
        for (int s = tid; s < R0S * R0S * 4; s += NTHR) {
            int sq = s & 3, ln = s >> 2;
            int rx = ln / R0S, ry = ln % R0S;
            int gx = wrap(X0 - 4 + rx), gy = wrap(Y0 - 4 + ry);
            float v[4];
            h2f4(xbIn + xbase + (gx * YDIM + gy) * TDIM + sq * 4, v);
            st4(xbS + ln * TDIM + sq * 4, v);
        }
        for (int s = tid; s < 17 * 16 * 4; s += NTHR) {
            int sq = s & 3, ln = s >> 2;
            int sx = ln / 16, sy = ln % 16;
            int gx = wrap(X0 - 4 + sx), gy = wrap(Y0 - 3 + sy);
            float v[4];
            h2f4(qIn + qbase + (gx * YDIM + gy) * TDIM + sq * 4, v);
            st4(q0S + ln * TDIM + sq * 4, v);
        }
        for (int s = tid; s < 16 * 17 * 4; s += NTHR) {
            int sq = s & 3, ln = s >> 2;
            int sx = ln / 17, sy = ln % 17;
            int gx = wrap(X0 - 3 + sx), gy = wrap(Y0 - 4 + sy);
            float v[4];
            h2f4(qIn + qbase + VOL + (gx * YDIM + gy) * TDIM + sq * 4, v);
            st4(q1S + ln * TDIM + sq * 4, v);
        }
    }

    // ---- phase 0b: per-slot persistent state (2 slots/thread) ----
    float p[2][4], xv[2][4], xb[2][4], q0[2][4], q1[2][4], q2[2][4];
    half4 XNr[2], L0r[2], L1r[2], L2r[2];
    #pragma unroll
    for (int m = 0; m < 2; ++m) {
        int line = 128 * m + (tid >> 2);
        int lx = line >> 4, ly = line & 15;
        int gx = wrap(X0 - 3 + lx), gy = wrap(Y0 - 3 + ly);
        int off  = xbase + (gx * YDIM + gy) * TDIM + t0;
        int qoff = qbase + (gx * YDIM + gy) * TDIM + t0;
        if (firstIter) {
            ld4(xraw + off, p[m]);
            #pragma unroll
            for (int j = 0; j < 4; ++j) { xv[m][j] = p[m][j]; q2[m][j] = 0.f; }
        } else {
            ld4(pIn + off, p[m]);
            ld4(xIn + off, xv[m]);
            h2f4(qIn + qoff + 2 * VOL, q2[m]);
        }
        XNr[m] = *(const half4*)(xnh + off);
        L0r[m] = *(const half4*)(lamh + qoff);
        L1r[m] = *(const half4*)(lamh + qoff + VOL);
        L2r[m] = *(const half4*)(lamh + qoff + 2 * VOL);
    }

    // ring lambdas (level-1 backward q rings at lx=-1 / ly=-1)
    half4 LRr;
    if (tid < 64) {
        int rly = tid >> 2;
        LRr = *(const half4*)(lamh + qbase +
              (wrap(X0 - 4) * YDIM + wrap(Y0 - 3 + rly)) * TDIM + t0);
    } else if (tid < 128) {
        int rlx = (tid - 64) >> 2;
        LRr = *(const half4*)(lamh + qbase + VOL +
              (wrap(X0 - 3 + rlx) * YDIM + wrap(Y0 - 4)) * TDIM + t0);
    }

    __syncthreads();

    // slot xbar from the staged LDS copy (same cvt value as global)
    #pragma unroll
    for (int m = 0; m < 2; ++m) {
        int line = 128 * m + (tid >> 2);
        int lx = line >> 4, ly = line & 15;
        ld4(xbS + ((lx + 1) * R0S + (ly + 1)) * TDIM + t0, xb[m]);
    }

    // ---- level loop: k = 1..4 ----
    #pragma unroll
    for (int k = 1; k <= 4; ++k) {
        const int lo = k - 1, hi = 17 - k;

        // ===== phase B: update p, q (own); write q0,q1 to LDS =====
        if (k == 1) {
            if (tid < 64) {
                int rly = tid >> 2;
                float qr[4], xbc[4], xpx[4];
                ld4(q0S + (0 * R1S + rly) * TDIM + t0, qr);
                ld4(xbS + (0 * R0S + (rly + 1)) * TDIM + t0, xbc);
                ld4(xbS + (1 * R0S + (rly + 1)) * TDIM + t0, xpx);
                #pragma unroll
                for (int j = 0; j < 4; ++j)
                    qr[j] = clampl(qr[j] + sigma * (xpx[j] - xbc[j]), (float)LRr[j]);
                st4(q0S + (0 * R1S + rly) * TDIM + t0, qr);
            } else if (tid < 128) {
                int rlx = (tid - 64) >> 2;
                float qr[4], xbc[4], xpy[4];
                ld4(q1S + (rlx * 17 + 0) * TDIM + t0, qr);
                ld4(xbS + ((rlx + 1) * R0S + 0) * TDIM + t0, xbc);
                ld4(xbS + ((rlx + 1) * R0S + 1) * TDIM + t0, xpy);
                #pragma unroll
                for (int j = 0; j < 4; ++j)
                    qr[j] = clampl(qr[j] + sigma * (xpy[j] - xbc[j]), (float)LRr[j]);
                st4(q1S + (rlx * 17 + 0) * TDIM + t0, qr);
            }
        }

        #pragma unroll
        for (int m = 0; m < 2; ++m) {
            int line = 128 * m + (tid >> 2);
            int lx = line >> 4, ly = line & 15;
            bool inX = (lx >= lo && lx < hi), inY = (ly >= lo && ly < hi);
            bool aq0 = inY && (lx >= lo - 1) && (lx < hi);
            bool aq1 = inX && (ly >= lo - 1) && (ly < hi);
            bool ax  = inX && inY;

            if (k == 1) {   // own q0,q1 from staged LDS (== global cvt / zeros)
                ld4(q0S + ((lx + 1) * R1S + ly) * TDIM + t0, q0[m]);
                ld4(q1S + (lx * 17 + (ly + 1)) * TDIM + t0, q1[m]);
            }
            if (aq0) {
                float xpx[4];
                ld4(xbS + ((lx + 2) * R0S + (ly + 1)) * TDIM + t0, xpx);
                #pragma unroll
                for (int j = 0; j < 4; ++j)
                    q0[m][j] = clampl(q0[m][j] + sigma * (xpx[j] - xb[m][j]),
                                      (float)L0r[m][j]);
                st4(q0S + ((lx + 1) * R1S + ly) * TDIM + t0, q0[m]);
            }
            if (aq1) {
                float xpy[4];
                ld4(xbS + ((lx + 1) * R0S + (ly + 2)) * TDIM + t0, xpy);
                #pragma unroll
                for (int j = 0; j < 4; ++j)
                    q1[m][j] = clampl(q1[m][j] + sigma * (xpy[j] - xb[m][j]),
                                      (float)L1r[m][j]);
                st4(q1S + (lx * 17 + (ly + 1)) * TDIM + t0, q1[m]);
            }
            if (ax) {
                float xb_tp = __shfl(xb[m][0], upSrc, 64);   // xbar at t0+4
                #pragma unroll
                for (int j = 0; j < 4; ++j) {
                    float gt = ((j < 3) ? xb[m][j + 1] : xb_tp) - xb[m][j];
                    q2[m][j] = clampl(q2[m][j] + sigma * gt, (float)L2r[m][j]);
                    p[m][j]  = (p[m][j] + sigma * (xb[m][j] - (float)XNr[m][j]))
                               * inv1ps;
                }
            }
        }
        __syncthreads();

        // ===== phase C: read backward q (new) from LDS; update x, xbar =====
        #pragma unroll
        for (int m = 0; m < 2; ++m) {
            int line = 128 * m + (tid >> 2);
            int lx = line >> 4, ly = line & 15;
            bool ax = (lx >= lo && lx < hi && ly >= lo && ly < hi);
            if (ax) {
                float q0b[4], q1b[4];
                ld4(q0S + (lx * R1S + ly) * TDIM + t0, q0b);       // (lx-1,ly)
                ld4(q1S + (lx * 17 + ly) * TDIM + t0, q1b);        // (lx,ly-1)
                float q2tm = __shfl(q2[m][3], dnSrc, 64);          // new, t0-1
                #pragma unroll
                for (int j = 0; j < 4; ++j) {
                    float q2p = (j == 0) ? q2tm : q2[m][j - 1];
                    float div = (q0b[j] - q0[m][j]) + (q1b[j] - q1[m][j])
                              + (q2p - q2[m][j]);
                    float xnew = xv[m][j] - tau * (p[m][j] + div);
                    xb[m][j] = xnew + theta * (xnew - xv[m][j]);
                    xv[m][j] = xnew;
                }
                if (k < 4)
                    st4(xbS + ((lx + 1) * R0S + (ly + 1)) * TDIM + t0, xb[m]);
            }
        }
        if (k < 4) __syncthreads();
    }

    // ---- output: center 10x10 lines ----
    #pragma unroll
    for (int m = 0; m < 2; ++m) {
        int line = 128 * m + (tid >> 2);
        int lx = line >> 4, ly = line & 15;
        if (lx >= 3 && lx < 13 && ly >= 3 && ly < 13) {
            int gx = X0 + lx - 3, gy = Y0 + ly - 3;
            int off  = xbase + (gx * YDIM + gy) * TDIM + t0;
            st4(xOut + off, xv[m]);
            if (!lastIter) {
                int qoff = qbase + (gx * YDIM + gy) * TDIM + t0;
                st4(pOut + off, p[m]);
                half4 h;
                h.x = (hreal)xb[m][0]; h.y = (hreal)xb[m][1];
                h.z = (hreal)xb[m][2]; h.w = (hreal)xb[m][3];
                *(half4*)(xbOut + off) = h;
                h.x = (hreal)q0[m][0]; h.y = (hreal)q0[m][1];
                h.z = (hreal)q0[m][2]; h.w = (hreal)q0[m][3];
                *(half4*)(qOut + qoff) = h;
                h.x = (hreal)q1[m][0]; h.y = (hreal)q1[m][1];
                h.z = (hreal)q1[m][2]; h.w = (hreal)q1[m][3];
                *(half4*)(qOut + qoff + VOL) = h;
                h.x = (hreal)q2[m][0]; h.y = (hreal)q2[m][1];
                h.z = (hreal)q2[m][2]; h.w = (hreal)q2[m][3];
                *(half4*)(qOut + qoff + 2 * VOL) = h;
            }
        }
    }
}

extern "C" void kernel_launch(void* const* d_in, const int* in_sizes, int n_in,
                              void* d_out, int out_size, void* d_ws, size_t ws_size,
                              hipStream_t stream) {
    const float* x   = (const float*)d_in[0];
    const float* lam = (const float*)d_in[1];
    float* out = (float*)d_out;
    float* ws  = (float*)d_ws;

    // ws: [pA|pB|xB] fp32 (3*NX floats) then fp16 region (12*NX halves)
    float* pA  = ws;
    float* pB  = ws + (size_t)NX;
    float* xBb = ws + (size_t)2 * NX;
    float* xAb = out;   // 12 launches: final (j=11, odd) writes A family -> d_out
    hreal* hb  = (hreal*)(ws + (size_t)3 * NX);
    hreal* xbAh = hb;
    hreal* xbBh = hb + (size_t)NX;
    hreal* qAh  = hb + (size_t)2 * NX;
    hreal* qBh  = hb + (size_t)5 * NX;
    hreal* lamh = hb + (size_t)8 * NX;
    hreal* xnh  = hb + (size_t)11 * NX;

    const double s10 = 1.0 / (1.0 + exp(-10.0));
    const double L   = sqrt(13.0);
    float sigma  = (float)(s10 / L);
    float tau    = sigma;
    float theta  = (float)s10;
    float inv1ps = (float)(1.0 / (1.0 + s10 / L));

    init_kernel<<<(3 * NX + 255) / 256, 256, 0, stream>>>(x, lam, lamh, xnh);

    for (int j = 0; j < T_ITERS / 4; ++j) {   // 12 launches
        const bool e = (j & 1) == 0;
        const int first = (j == 0) ? 1 : 0;
        const int last  = (j == T_ITERS / 4 - 1) ? 1 : 0;
        pd_step4<<<NBLK, NTHR, 0, stream>>>(
            xnh, lamh, x,
            e ? pA : pB,   e ? pB : pA,
            e ? xAb : xBb, e ? xBb : xAb,
            e ? xbAh : xbBh, e ? xbBh : xbAh,
            e ? qAh : qBh,  e ? qBh : qAh,
            sigma, inv1ps, tau, theta, first, last);
    }
}